// Round 1
// baseline (348.658 us; speedup 1.0000x reference)
//
#include <hip/hip_runtime.h>
#include <hip/hip_bf16.h>
#include <stdint.h>

typedef unsigned short u16;
typedef __bf16 bf16x8 __attribute__((ext_vector_type(8)));
typedef float f32x4 __attribute__((ext_vector_type(4)));

#define SEQ    2048
#define DMODEL 2048
#define NHEAD  16
#define DHEAD  128
#define ATT_SCALE 0.088388347648318447f   // 1/sqrt(128)

__device__ __forceinline__ u16 f2bf(float f){
  uint32_t u = __float_as_uint(f);
  u += 0x7FFFu + ((u >> 16) & 1u);        // round-to-nearest-even
  return (u16)(u >> 16);
}

__device__ __forceinline__ void gload_lds16(const u16* g, u16* l){
  __builtin_amdgcn_global_load_lds((const __attribute__((address_space(1))) void*)g,
                                   (__attribute__((address_space(3))) void*)l,
                                   16, 0, 0);
}

// ---------------- f32 -> bf16 conversion (vectorized) ----------------
__global__ __launch_bounds__(256) void cvt_bf16(const float* __restrict__ src,
                                                u16* __restrict__ dst, int n4){
  int i = blockIdx.x * 256 + threadIdx.x;
  if (i < n4){
    float4 v = reinterpret_cast<const float4*>(src)[i];
    ushort4 o;
    o.x = f2bf(v.x); o.y = f2bf(v.y); o.z = f2bf(v.z); o.w = f2bf(v.w);
    reinterpret_cast<ushort4*>(dst)[i] = o;
  }
}

// ---------------- GEMM core: C = A(M,K) x W(N,K)^T ----------------
// 128x128 tile, BK=32, 4 waves (2x2 of 64x64), global_load_lds staging,
// 4-chunk XOR swizzle on LDS rows (pre-swizzled global source).
__device__ __forceinline__ void gemm_core(const u16* __restrict__ A,
                                          const u16* __restrict__ W,
                                          int bm, int bn,
                                          u16* ldsA, u16* ldsB,
                                          f32x4 acc[4][4]){
  const int tid  = threadIdx.x;
  const int wid  = tid >> 6, lane = tid & 63;
  const int g    = lane >> 4, ln = lane & 15;
  const int wr   = wid >> 1, wc = wid & 1;
  const f32x4 z4 = {0.f, 0.f, 0.f, 0.f};
  #pragma unroll
  for (int m = 0; m < 4; ++m)
    #pragma unroll
    for (int n = 0; n < 4; ++n) acc[m][n] = z4;

  for (int k0 = 0; k0 < DMODEL; k0 += 32){
    __syncthreads();
    #pragma unroll
    for (int is = 0; is < 2; ++is){
      int o   = (wid*2 + is)*1024 + lane*16;   // byte offset in 8KB tile
      int row = o >> 6;                         // 64B per row (32 bf16)
      int sc  = ((o >> 4) & 3) ^ (row & 3);     // source chunk (inverse swizzle)
      gload_lds16(A + (size_t)(bm + row)*DMODEL + k0 + sc*8, ldsA + (wid*2+is)*512);
      gload_lds16(W + (size_t)(bn + row)*DMODEL + k0 + sc*8, ldsB + (wid*2+is)*512);
    }
    __syncthreads();
    bf16x8 a[4], b[4];
    #pragma unroll
    for (int m = 0; m < 4; ++m){
      int row = wr*64 + m*16 + ln;
      int ch  = g ^ (row & 3);
      a[m] = *reinterpret_cast<const bf16x8*>(ldsA + row*32 + ch*8);
    }
    #pragma unroll
    for (int n = 0; n < 4; ++n){
      int row = wc*64 + n*16 + ln;
      int ch  = g ^ (row & 3);
      b[n] = *reinterpret_cast<const bf16x8*>(ldsB + row*32 + ch*8);
    }
    #pragma unroll
    for (int m = 0; m < 4; ++m)
      #pragma unroll
      for (int n = 0; n < 4; ++n)
        acc[m][n] = __builtin_amdgcn_mfma_f32_16x16x32_bf16(a[m], b[n], acc[m][n], 0, 0, 0);
  }
}

// QKV projection: z=0 -> Q (bf16 row-major), z=1 -> K (bf16 row-major),
// z=2 -> V stored transposed as (B*H, DHEAD, SEQ).
__global__ __launch_bounds__(256) void gemm_qkv(const u16* __restrict__ A,
    const u16* __restrict__ Wq, const u16* __restrict__ Wk, const u16* __restrict__ Wv,
    u16* __restrict__ Q, u16* __restrict__ K, u16* __restrict__ Vt){
  __shared__ __align__(16) u16 ldsA[128*32];
  __shared__ __align__(16) u16 ldsB[128*32];
  const int z = blockIdx.z;
  const u16* W = (z == 0) ? Wq : (z == 1) ? Wk : Wv;
  const int bm = blockIdx.x * 128, bn = blockIdx.y * 128;
  f32x4 acc[4][4];
  gemm_core(A, W, bm, bn, ldsA, ldsB, acc);
  const int tid = threadIdx.x;
  const int wid = tid >> 6, lane = tid & 63;
  const int g = lane >> 4, ln = lane & 15;
  const int wr = wid >> 1, wc = wid & 1;
  if (z < 2){
    u16* C = (z == 0) ? Q : K;
    #pragma unroll
    for (int m = 0; m < 4; ++m)
      #pragma unroll
      for (int n = 0; n < 4; ++n){
        int col = bn + wc*64 + n*16 + ln;
        #pragma unroll
        for (int i = 0; i < 4; ++i){
          int row = bm + wr*64 + m*16 + g*4 + i;
          C[(size_t)row*DMODEL + col] = f2bf(acc[m][n][i]);
        }
      }
  } else {
    #pragma unroll
    for (int m = 0; m < 4; ++m)
      #pragma unroll
      for (int n = 0; n < 4; ++n){
        int col  = bn + wc*64 + n*16 + ln;     // h*128 + d
        int row0 = bm + wr*64 + m*16 + g*4;    // 4 consecutive tokens
        int bb   = row0 >> 11, lt = row0 & (SEQ-1);
        ushort4 pk;
        pk.x = f2bf(acc[m][n][0]); pk.y = f2bf(acc[m][n][1]);
        pk.z = f2bf(acc[m][n][2]); pk.w = f2bf(acc[m][n][3]);
        // Vt[(bb*NHEAD+h)*DHEAD + d][lt] ; (bb*16+h)*128+d == bb*DMODEL+col
        *reinterpret_cast<ushort4*>(Vt + (size_t)(bb*DMODEL + col)*SEQ + lt) = pk;
      }
  }
}

// Output projection: fp32 epilogue straight to d_out.
__global__ __launch_bounds__(256) void gemm_out(const u16* __restrict__ A,
    const u16* __restrict__ Wo, float* __restrict__ C){
  __shared__ __align__(16) u16 ldsA[128*32];
  __shared__ __align__(16) u16 ldsB[128*32];
  const int bm = blockIdx.x * 128, bn = blockIdx.y * 128;
  f32x4 acc[4][4];
  gemm_core(A, Wo, bm, bn, ldsA, ldsB, acc);
  const int tid = threadIdx.x;
  const int wid = tid >> 6, lane = tid & 63;
  const int g = lane >> 4, ln = lane & 15;
  const int wr = wid >> 1, wc = wid & 1;
  #pragma unroll
  for (int m = 0; m < 4; ++m)
    #pragma unroll
    for (int n = 0; n < 4; ++n){
      int col = bn + wc*64 + n*16 + ln;
      #pragma unroll
      for (int i = 0; i < 4; ++i){
        int row = bm + wr*64 + m*16 + g*4 + i;
        C[(size_t)row*DMODEL + col] = acc[m][n][i];
      }
    }
}

// ---------------- causal flash attention ----------------
// grid (SEQ/64, B*H), 4 waves; wave w owns q rows [qt*64+w*16, +16).
// KV tile = 64. K staged [64][128] (row-XOR-swizzled), V^T staged [128][64]
// (row-XOR-swizzled), P via 2KB/wave swizzled LDS.
__global__ __launch_bounds__(256) void attn_fwd(const u16* __restrict__ Qb,
    const u16* __restrict__ Kb, const u16* __restrict__ Vtb, u16* __restrict__ Yb){
  __shared__ __align__(16) u16 Kt[64*128];
  __shared__ __align__(16) u16 Vt[128*64];
  __shared__ __align__(16) u16 Pl[4][16*64];
  const int tid = threadIdx.x, w = tid >> 6, lane = tid & 63;
  const int g = lane >> 4, ln = lane & 15;
  const int qt = blockIdx.x, bh = blockIdx.y;
  const int b = bh >> 4, h = bh & 15;
  const int qw = qt*64 + w*16;           // wave's q base within sequence

  bf16x8 qf[4];
  {
    const u16* qp = Qb + (size_t)(b*SEQ + qw + ln)*DMODEL + h*DHEAD + g*8;
    #pragma unroll
    for (int c = 0; c < 4; ++c) qf[c] = *reinterpret_cast<const bf16x8*>(qp + c*32);
  }
  float mrun = -1e30f, lrun = 0.f;
  f32x4 yacc[8];
  {
    const f32x4 z4 = {0.f,0.f,0.f,0.f};
    #pragma unroll
    for (int dt = 0; dt < 8; ++dt) yacc[dt] = z4;
  }

  for (int t = 0; t <= qt; ++t){
    __syncthreads();
    #pragma unroll
    for (int is = 0; is < 4; ++is){
      int o = w*4096 + is*1024 + lane*16;
      {
        int row = o >> 8;                         // K rows: 256B each
        int sc  = ((o >> 4) & 15) ^ (row & 7);
        gload_lds16(Kb + (size_t)(b*SEQ + t*64 + row)*DMODEL + h*DHEAD + sc*8,
                    Kt + w*2048 + is*512);
      }
      {
        int row = o >> 7;                         // V^T rows: 128B each
        int sc  = ((o >> 4) & 7) ^ (row & 7);
        gload_lds16(Vtb + (size_t)(bh*DHEAD + row)*SEQ + t*64 + sc*8,
                    Vt + w*2048 + is*512);
      }
    }
    __syncthreads();

    // S^T = K · Q^T  (lane: q = ln, k = kt*16 + g*4 + i)
    f32x4 st[4];
    #pragma unroll
    for (int kt = 0; kt < 4; ++kt){
      f32x4 accs = {0.f,0.f,0.f,0.f};
      #pragma unroll
      for (int c = 0; c < 4; ++c){
        int row = kt*16 + ln;
        int ch  = (c*4 + g) ^ (row & 7);
        bf16x8 kf = *reinterpret_cast<const bf16x8*>(Kt + row*128 + ch*8);
        accs = __builtin_amdgcn_mfma_f32_16x16x32_bf16(kf, qf[c], accs, 0, 0, 0);
      }
      st[kt] = accs;
    }

    // online softmax
    float p[16];
    float tmax = -1e30f;
    #pragma unroll
    for (int kt = 0; kt < 4; ++kt)
      #pragma unroll
      for (int i = 0; i < 4; ++i){
        float s = st[kt][i] * ATT_SCALE;
        if (t == qt && (kt*16 + g*4 + i) > (w*16 + ln)) s = -1e30f;
        p[kt*4+i] = s;
        tmax = fmaxf(tmax, s);
      }
    tmax = fmaxf(tmax, __shfl_xor(tmax, 16));
    tmax = fmaxf(tmax, __shfl_xor(tmax, 32));
    float mn = fmaxf(mrun, tmax);
    float psum = 0.f;
    #pragma unroll
    for (int j = 0; j < 16; ++j){ p[j] = __expf(p[j] - mn); psum += p[j]; }
    psum += __shfl_xor(psum, 16);
    psum += __shfl_xor(psum, 32);
    float fr = __expf(mrun - mn);
    lrun = lrun*fr + psum;
    mrun = mn;
    float fi[4];
    #pragma unroll
    for (int i = 0; i < 4; ++i) fi[i] = __shfl(fr, g*4 + i);
    #pragma unroll
    for (int dt = 0; dt < 8; ++dt)
      #pragma unroll
      for (int i = 0; i < 4; ++i) yacc[dt][i] *= fi[i];

    // P -> LDS (per-wave [16 q][64 k], 128B rows, chunk ^= q&7)
    u16* pw = &Pl[w][0];
    #pragma unroll
    for (int kt = 0; kt < 4; ++kt)
      #pragma unroll
      for (int pr = 0; pr < 2; ++pr){
        uint32_t pk = (uint32_t)f2bf(p[kt*4 + 2*pr]) |
                      ((uint32_t)f2bf(p[kt*4 + 2*pr + 1]) << 16);
        int byte = (kt*16 + g*4 + 2*pr)*2;        // byte within row
        int ch   = (byte >> 4) ^ (ln & 7);
        int addr = ln*128 + (ch << 4) + (byte & 15);
        *reinterpret_cast<uint32_t*>(reinterpret_cast<char*>(pw) + addr) = pk;
      }

    // PV: yacc[dt] += P(16q x 32k) · V(32k x 16d)
    #pragma unroll
    for (int kc = 0; kc < 2; ++kc){
      int chp = (kc*4 + g) ^ (ln & 7);
      bf16x8 pf = *reinterpret_cast<const bf16x8*>(pw + ln*64 + chp*8);
      #pragma unroll
      for (int dt = 0; dt < 8; ++dt){
        int row = dt*16 + ln;
        int chv = (kc*4 + g) ^ (row & 7);
        bf16x8 vf = *reinterpret_cast<const bf16x8*>(Vt + row*64 + chv*8);
        yacc[dt] = __builtin_amdgcn_mfma_f32_16x16x32_bf16(pf, vf, yacc[dt], 0, 0, 0);
      }
    }
  }

  // epilogue: y /= l, store bf16 merged-head layout
  float inv[4];
  #pragma unroll
  for (int i = 0; i < 4; ++i){
    float li = __shfl(lrun, g*4 + i);
    inv[i] = 1.0f / li;
  }
  #pragma unroll
  for (int dt = 0; dt < 8; ++dt)
    #pragma unroll
    for (int i = 0; i < 4; ++i){
      Yb[(size_t)(b*SEQ + qw + g*4 + i)*DMODEL + h*DHEAD + dt*16 + ln] =
          f2bf(yacc[dt][i] * inv[i]);
    }
}

// ---------------- launcher ----------------
extern "C" void kernel_launch(void* const* d_in, const int* in_sizes, int n_in,
                              void* d_out, int out_size, void* d_ws, size_t ws_size,
                              hipStream_t stream) {
  const float* x  = (const float*)d_in[0];
  const float* Wq = (const float*)d_in[1];
  const float* Wk = (const float*)d_in[2];
  const float* Wv = (const float*)d_in[3];
  const float* Wo = (const float*)d_in[4];
  float* out = (float*)d_out;

  char* ws = (char*)d_ws;
  u16* xb  = (u16*)(ws +          0);  // 16 MB  (B*L*D bf16)
  u16* Wqb = (u16*)(ws + 16777216);    // 8 MB each
  u16* Wkb = (u16*)(ws + 25165824);
  u16* Wvb = (u16*)(ws + 33554432);
  u16* Wob = (u16*)(ws + 41943040);
  u16* Qb  = (u16*)(ws + 50331648);    // 16 MB
  u16* Kb  = (u16*)(ws + 67108864);    // 16 MB
  u16* Vtb = (u16*)(ws + 83886080);    // 16 MB (B*H, DHEAD, SEQ)
  u16* Yb  = (u16*)(ws + 100663296);   // 16 MB

  // conversions
  cvt_bf16<<<dim3(8192), 256, 0, stream>>>(x,  xb,  2097152);
  cvt_bf16<<<dim3(4096), 256, 0, stream>>>(Wq, Wqb, 1048576);
  cvt_bf16<<<dim3(4096), 256, 0, stream>>>(Wk, Wkb, 1048576);
  cvt_bf16<<<dim3(4096), 256, 0, stream>>>(Wv, Wvb, 1048576);
  cvt_bf16<<<dim3(4096), 256, 0, stream>>>(Wo, Wob, 1048576);

  // QKV projections (z=0:Q, z=1:K, z=2:V-transposed)
  gemm_qkv<<<dim3(32, 16, 3), 256, 0, stream>>>(xb, Wqb, Wkb, Wvb, Qb, Kb, Vtb);

  // causal flash attention
  attn_fwd<<<dim3(32, 32), 256, 0, stream>>>(Qb, Kb, Vtb, Yb);

  // output projection (fp32 out)
  gemm_out<<<dim3(32, 16), 256, 0, stream>>>(Yb, Wob, out);
}

// Round 2
// 337.078 us; speedup vs baseline: 1.0344x; 1.0344x over previous
//
#include <hip/hip_runtime.h>
#include <hip/hip_bf16.h>
#include <stdint.h>

typedef unsigned short u16;
typedef __bf16 bf16x8 __attribute__((ext_vector_type(8)));
typedef float f32x4 __attribute__((ext_vector_type(4)));

#define SEQ    2048
#define DMODEL 2048
#define NHEAD  16
#define DHEAD  128
// 1/sqrt(128) * log2(e): Q is pre-scaled so QK^T lands directly in exp2 domain
#define QSCALE (0.088388347648318447f * 1.4426950408889634f)

__device__ __forceinline__ u16 f2bf(float f){
  uint32_t u = __float_as_uint(f);
  u += 0x7FFFu + ((u >> 16) & 1u);        // round-to-nearest-even
  return (u16)(u >> 16);
}

__device__ __forceinline__ void gload_lds16(const u16* g, u16* l){
  __builtin_amdgcn_global_load_lds((const __attribute__((address_space(1))) void*)g,
                                   (__attribute__((address_space(3))) void*)l,
                                   16, 0, 0);
}

// ---------------- f32 -> bf16 conversion (vectorized) ----------------
__global__ __launch_bounds__(256) void cvt_bf16(const float* __restrict__ src,
                                                u16* __restrict__ dst, int n4){
  int i = blockIdx.x * 256 + threadIdx.x;
  if (i < n4){
    float4 v = reinterpret_cast<const float4*>(src)[i];
    ushort4 o;
    o.x = f2bf(v.x); o.y = f2bf(v.y); o.z = f2bf(v.z); o.w = f2bf(v.w);
    reinterpret_cast<ushort4*>(dst)[i] = o;
  }
}

// ---------------- GEMM core: C = A(M,K) x W(N,K)^T ----------------
__device__ __forceinline__ void gemm_core(const u16* __restrict__ A,
                                          const u16* __restrict__ W,
                                          int bm, int bn,
                                          u16* ldsA, u16* ldsB,
                                          f32x4 acc[4][4]){
  const int tid  = threadIdx.x;
  const int wid  = tid >> 6, lane = tid & 63;
  const int g    = lane >> 4, ln = lane & 15;
  const int wr   = wid >> 1, wc = wid & 1;
  const f32x4 z4 = {0.f, 0.f, 0.f, 0.f};
  #pragma unroll
  for (int m = 0; m < 4; ++m)
    #pragma unroll
    for (int n = 0; n < 4; ++n) acc[m][n] = z4;

  for (int k0 = 0; k0 < DMODEL; k0 += 32){
    __syncthreads();
    #pragma unroll
    for (int is = 0; is < 2; ++is){
      int o   = (wid*2 + is)*1024 + lane*16;
      int row = o >> 6;
      int sc  = ((o >> 4) & 3) ^ (row & 3);
      gload_lds16(A + (size_t)(bm + row)*DMODEL + k0 + sc*8, ldsA + (wid*2+is)*512);
      gload_lds16(W + (size_t)(bn + row)*DMODEL + k0 + sc*8, ldsB + (wid*2+is)*512);
    }
    __syncthreads();
    bf16x8 a[4], b[4];
    #pragma unroll
    for (int m = 0; m < 4; ++m){
      int row = wr*64 + m*16 + ln;
      int ch  = g ^ (row & 3);
      a[m] = *reinterpret_cast<const bf16x8*>(ldsA + row*32 + ch*8);
    }
    #pragma unroll
    for (int n = 0; n < 4; ++n){
      int row = wc*64 + n*16 + ln;
      int ch  = g ^ (row & 3);
      b[n] = *reinterpret_cast<const bf16x8*>(ldsB + row*32 + ch*8);
    }
    #pragma unroll
    for (int m = 0; m < 4; ++m)
      #pragma unroll
      for (int n = 0; n < 4; ++n)
        acc[m][n] = __builtin_amdgcn_mfma_f32_16x16x32_bf16(a[m], b[n], acc[m][n], 0, 0, 0);
  }
}

// QKV projection: z=0 -> Q (bf16, pre-scaled by QSCALE), z=1 -> K,
// z=2 -> V stored transposed as (B*H, DHEAD, SEQ).
__global__ __launch_bounds__(256) void gemm_qkv(const u16* __restrict__ A,
    const u16* __restrict__ Wq, const u16* __restrict__ Wk, const u16* __restrict__ Wv,
    u16* __restrict__ Q, u16* __restrict__ K, u16* __restrict__ Vt){
  __shared__ __align__(16) u16 ldsA[128*32];
  __shared__ __align__(16) u16 ldsB[128*32];
  const int z = blockIdx.z;
  const u16* W = (z == 0) ? Wq : (z == 1) ? Wk : Wv;
  const int bm = blockIdx.x * 128, bn = blockIdx.y * 128;
  f32x4 acc[4][4];
  gemm_core(A, W, bm, bn, ldsA, ldsB, acc);
  const int tid = threadIdx.x;
  const int wid = tid >> 6, lane = tid & 63;
  const int g = lane >> 4, ln = lane & 15;
  const int wr = wid >> 1, wc = wid & 1;
  if (z < 2){
    u16* C = (z == 0) ? Q : K;
    const float sc = (z == 0) ? QSCALE : 1.0f;
    #pragma unroll
    for (int m = 0; m < 4; ++m)
      #pragma unroll
      for (int n = 0; n < 4; ++n){
        int col = bn + wc*64 + n*16 + ln;
        #pragma unroll
        for (int i = 0; i < 4; ++i){
          int row = bm + wr*64 + m*16 + g*4 + i;
          C[(size_t)row*DMODEL + col] = f2bf(acc[m][n][i] * sc);
        }
      }
  } else {
    #pragma unroll
    for (int m = 0; m < 4; ++m)
      #pragma unroll
      for (int n = 0; n < 4; ++n){
        int col  = bn + wc*64 + n*16 + ln;
        int row0 = bm + wr*64 + m*16 + g*4;
        int bb   = row0 >> 11, lt = row0 & (SEQ-1);
        ushort4 pk;
        pk.x = f2bf(acc[m][n][0]); pk.y = f2bf(acc[m][n][1]);
        pk.z = f2bf(acc[m][n][2]); pk.w = f2bf(acc[m][n][3]);
        *reinterpret_cast<ushort4*>(Vt + (size_t)(bb*DMODEL + col)*SEQ + lt) = pk;
      }
  }
}

// Output projection: fp32 epilogue straight to d_out.
__global__ __launch_bounds__(256) void gemm_out(const u16* __restrict__ A,
    const u16* __restrict__ Wo, float* __restrict__ C){
  __shared__ __align__(16) u16 ldsA[128*32];
  __shared__ __align__(16) u16 ldsB[128*32];
  const int bm = blockIdx.x * 128, bn = blockIdx.y * 128;
  f32x4 acc[4][4];
  gemm_core(A, Wo, bm, bn, ldsA, ldsB, acc);
  const int tid = threadIdx.x;
  const int wid = tid >> 6, lane = tid & 63;
  const int g = lane >> 4, ln = lane & 15;
  const int wr = wid >> 1, wc = wid & 1;
  #pragma unroll
  for (int m = 0; m < 4; ++m)
    #pragma unroll
    for (int n = 0; n < 4; ++n){
      int col = bn + wc*64 + n*16 + ln;
      #pragma unroll
      for (int i = 0; i < 4; ++i){
        int row = bm + wr*64 + m*16 + g*4 + i;
        C[(size_t)row*DMODEL + col] = acc[m][n][i];
      }
    }
}

// ---------------- causal flash attention v2 ----------------
// 4 waves x 16 q-rows; KVBLK=64; double-buffered K/V via global_load_lds
// with 2-phase prefetch (raw s_barrier + inline vmcnt so prefetch overlaps
// compute); exp2-domain softmax (Q pre-scaled); defer-max rescale; causal
// mask hoisted to a separate diagonal-tile epilogue.

__device__ __forceinline__ void attn_stage(const u16* __restrict__ Kb,
    const u16* __restrict__ Vtb, u16* Kd, u16* Vd,
    int b, int bh, int h, int t, int w, int lane){
  #pragma unroll
  for (int is = 0; is < 4; ++is){
    int o = w*4096 + is*1024 + lane*16;
    int rowK = o >> 8;                         // K rows: 256B each
    int scK  = ((o >> 4) & 15) ^ (rowK & 7);
    gload_lds16(Kb + (size_t)(b*SEQ + t*64 + rowK)*DMODEL + h*DHEAD + scK*8,
                Kd + w*2048 + is*512);
    int rowV = o >> 7;                         // V^T rows: 128B each
    int scV  = ((o >> 4) & 7) ^ (rowV & 7);
    gload_lds16(Vtb + (size_t)(bh*DHEAD + rowV)*SEQ + t*64 + scV*8,
                Vd + w*2048 + is*512);
  }
}

template<bool MASKED>
__device__ __forceinline__ void attn_tile(const u16* Kc, const u16* Vc, u16* pw,
                                          const bf16x8 qf[4], f32x4 yacc[8],
                                          float& mrun, float& lrun,
                                          int w, int lane){
  const int g = lane >> 4, ln = lane & 15;
  // S^T = K · Q^T  (lane: q = ln, k = kt*16 + g*4 + i), exp2 domain already
  f32x4 st[4];
  __builtin_amdgcn_s_setprio(1);
  #pragma unroll
  for (int kt = 0; kt < 4; ++kt){
    f32x4 accs = {0.f,0.f,0.f,0.f};
    #pragma unroll
    for (int c = 0; c < 4; ++c){
      int row = kt*16 + ln;
      int ch  = (c*4 + g) ^ (row & 7);
      bf16x8 kf = *reinterpret_cast<const bf16x8*>(Kc + row*128 + ch*8);
      accs = __builtin_amdgcn_mfma_f32_16x16x32_bf16(kf, qf[c], accs, 0, 0, 0);
    }
    st[kt] = accs;
  }
  __builtin_amdgcn_s_setprio(0);

  float p[16];
  float tmax = -1e30f;
  #pragma unroll
  for (int kt = 0; kt < 4; ++kt)
    #pragma unroll
    for (int i = 0; i < 4; ++i){
      float s = st[kt][i];
      if (MASKED && (kt*16 + g*4 + i) > (w*16 + ln)) s = -1e30f;
      p[kt*4+i] = s;
      tmax = fmaxf(tmax, s);
    }
  tmax = fmaxf(tmax, __shfl_xor(tmax, 16));
  tmax = fmaxf(tmax, __shfl_xor(tmax, 32));

  // defer-max: only rescale when the tile max grew past threshold (exp2 dom)
  if (!__all(tmax - mrun <= 11.5f)){
    float mn = fmaxf(mrun, tmax);
    float fr = __builtin_amdgcn_exp2f(mrun - mn);
    lrun *= fr;
    float fi[4];
    #pragma unroll
    for (int i = 0; i < 4; ++i) fi[i] = __shfl(fr, g*4 + i);
    #pragma unroll
    for (int dt = 0; dt < 8; ++dt)
      #pragma unroll
      for (int i = 0; i < 4; ++i) yacc[dt][i] *= fi[i];
    mrun = mn;
  }
  float psum = 0.f;
  #pragma unroll
  for (int j = 0; j < 16; ++j){
    p[j] = __builtin_amdgcn_exp2f(p[j] - mrun);
    psum += p[j];
  }
  psum += __shfl_xor(psum, 16);
  psum += __shfl_xor(psum, 32);
  lrun += psum;

  // P -> LDS (per-wave [16 q][64 k], 128B rows, chunk ^= q&7)
  #pragma unroll
  for (int kt = 0; kt < 4; ++kt)
    #pragma unroll
    for (int pr = 0; pr < 2; ++pr){
      uint32_t pk = (uint32_t)f2bf(p[kt*4 + 2*pr]) |
                    ((uint32_t)f2bf(p[kt*4 + 2*pr + 1]) << 16);
      int byte = (kt*16 + g*4 + 2*pr)*2;
      int ch   = (byte >> 4) ^ (ln & 7);
      int addr = ln*128 + (ch << 4) + (byte & 15);
      *reinterpret_cast<uint32_t*>(reinterpret_cast<char*>(pw) + addr) = pk;
    }

  // PV: yacc[dt] += P(16q x 64k) · V(64k x 128d)
  __builtin_amdgcn_s_setprio(1);
  #pragma unroll
  for (int kc = 0; kc < 2; ++kc){
    int chp = (kc*4 + g) ^ (ln & 7);
    bf16x8 pf = *reinterpret_cast<const bf16x8*>(pw + ln*64 + chp*8);
    #pragma unroll
    for (int dt = 0; dt < 8; ++dt){
      int row = dt*16 + ln;
      int chv = (kc*4 + g) ^ (row & 7);
      bf16x8 vf = *reinterpret_cast<const bf16x8*>(Vc + row*64 + chv*8);
      yacc[dt] = __builtin_amdgcn_mfma_f32_16x16x32_bf16(pf, vf, yacc[dt], 0, 0, 0);
    }
  }
  __builtin_amdgcn_s_setprio(0);
}

__global__ __launch_bounds__(256) void attn_fwd(const u16* __restrict__ Qb,
    const u16* __restrict__ Kb, const u16* __restrict__ Vtb, u16* __restrict__ Yb){
  __shared__ __align__(16) u16 Kt[2][64*128];
  __shared__ __align__(16) u16 Vt[2][128*64];
  __shared__ __align__(16) u16 Pl[4][16*64];
  const int tid = threadIdx.x, w = tid >> 6, lane = tid & 63;
  const int g = lane >> 4, ln = lane & 15;
  const int qt = (SEQ/64 - 1) - blockIdx.x;     // LPT: long blocks first
  const int bh = blockIdx.y;
  const int b = bh >> 4, h = bh & 15;
  const int qw = qt*64 + w*16;

  bf16x8 qf[4];
  {
    const u16* qp = Qb + (size_t)(b*SEQ + qw + ln)*DMODEL + h*DHEAD + g*8;
    #pragma unroll
    for (int c = 0; c < 4; ++c) qf[c] = *reinterpret_cast<const bf16x8*>(qp + c*32);
  }
  float mrun = -1e30f, lrun = 0.f;
  f32x4 yacc[8];
  {
    const f32x4 z4 = {0.f,0.f,0.f,0.f};
    #pragma unroll
    for (int dt = 0; dt < 8; ++dt) yacc[dt] = z4;
  }

  // prologue: stage tile 0, drain, barrier
  attn_stage(Kb, Vtb, &Kt[0][0], &Vt[0][0], b, bh, h, 0, w, lane);
  asm volatile("s_waitcnt vmcnt(0)" ::: "memory");
  __builtin_amdgcn_s_barrier();

  int cur = 0;
  for (int t = 0; t < qt; ++t){
    // issue next tile's loads (targets other buffer) — overlaps with compute
    attn_stage(Kb, Vtb, &Kt[cur^1][0], &Vt[cur^1][0], b, bh, h, t+1, w, lane);
    attn_tile<false>(&Kt[cur][0], &Vt[cur][0], &Pl[w][0], qf, yacc, mrun, lrun, w, lane);
    asm volatile("s_waitcnt vmcnt(0) lgkmcnt(0)" ::: "memory");
    __builtin_amdgcn_s_barrier();
    cur ^= 1;
  }
  // diagonal tile (masked), no prefetch
  attn_tile<true>(&Kt[cur][0], &Vt[cur][0], &Pl[w][0], qf, yacc, mrun, lrun, w, lane);

  // epilogue: y /= l, store bf16 merged-head layout
  float inv[4];
  #pragma unroll
  for (int i = 0; i < 4; ++i){
    float li = __shfl(lrun, g*4 + i);
    inv[i] = __builtin_amdgcn_rcpf(li);
  }
  #pragma unroll
  for (int dt = 0; dt < 8; ++dt)
    #pragma unroll
    for (int i = 0; i < 4; ++i){
      Yb[(size_t)(b*SEQ + qw + g*4 + i)*DMODEL + h*DHEAD + dt*16 + ln] =
          f2bf(yacc[dt][i] * inv[i]);
    }
}

// ---------------- launcher ----------------
extern "C" void kernel_launch(void* const* d_in, const int* in_sizes, int n_in,
                              void* d_out, int out_size, void* d_ws, size_t ws_size,
                              hipStream_t stream) {
  const float* x  = (const float*)d_in[0];
  const float* Wq = (const float*)d_in[1];
  const float* Wk = (const float*)d_in[2];
  const float* Wv = (const float*)d_in[3];
  const float* Wo = (const float*)d_in[4];
  float* out = (float*)d_out;

  char* ws = (char*)d_ws;
  u16* xb  = (u16*)(ws +          0);
  u16* Wqb = (u16*)(ws + 16777216);
  u16* Wkb = (u16*)(ws + 25165824);
  u16* Wvb = (u16*)(ws + 33554432);
  u16* Wob = (u16*)(ws + 41943040);
  u16* Qb  = (u16*)(ws + 50331648);
  u16* Kb  = (u16*)(ws + 67108864);
  u16* Vtb = (u16*)(ws + 83886080);
  u16* Yb  = (u16*)(ws + 100663296);

  cvt_bf16<<<dim3(8192), 256, 0, stream>>>(x,  xb,  2097152);
  cvt_bf16<<<dim3(4096), 256, 0, stream>>>(Wq, Wqb, 1048576);
  cvt_bf16<<<dim3(4096), 256, 0, stream>>>(Wk, Wkb, 1048576);
  cvt_bf16<<<dim3(4096), 256, 0, stream>>>(Wv, Wvb, 1048576);
  cvt_bf16<<<dim3(4096), 256, 0, stream>>>(Wo, Wob, 1048576);

  gemm_qkv<<<dim3(32, 16, 3), 256, 0, stream>>>(xb, Wqb, Wkb, Wvb, Qb, Kb, Vtb);

  attn_fwd<<<dim3(32, 32), 256, 0, stream>>>(Qb, Kb, Vtb, Yb);

  gemm_out<<<dim3(32, 16), 256, 0, stream>>>(Yb, Wob, out);
}